// Round 3
// baseline (3891.734 us; speedup 1.0000x reference)
//
#include <hip/hip_runtime.h>
#include <math.h>

// ============================================================================
// Transformer block, fp32 baseline (round 2 — resubmission of the audited
// workspace-safe round-1 kernel; round-2 bench failed at GPU acquisition).
// B=4, S=2048, D=1024, H=16, dk=64, F=4096.
//
// Workspace plan (TD = 8192*1024 floats = 32 MB):
//   ws+0TD : h   (LN1 out)  -> reused as ctx (attention output)
//   ws+1TD : q               -> reused as h2 (LN2 out)
//   ws+2TD : k   \___ dead after attention; region [2TD, 2TD+chunkTD) reused
//   ws+3TD : v   /    as the GELU'd FFN chunk buffer
//   d_out  : x1 (attn residual) — final GEMM reads res==C per-thread, safe.
//   d_out[0:4096] : vsum (consumed by attention, overwritten later).
// Peak ws usage: max(4TD, 2TD + chunkTD) floats.
//   chunk=2048 -> 128 MB;  chunk=4096 (if ws_size >= 192 MB) -> 192 MB.
// ============================================================================

#define NEGV (-1.0e9f)

// ---------------------------------------------------------------- LayerNorm
__global__ __launch_bounds__(256) void ln_f32(
    const float* __restrict__ X, const float* __restrict__ G,
    const float* __restrict__ Bt, float* __restrict__ O) {
  int row = blockIdx.x, t = threadIdx.x;
  const float* xr = X + (size_t)row * 1024;
  float4 x4 = *(const float4*)(xr + t * 4);
  float s = x4.x + x4.y + x4.z + x4.w;
#pragma unroll
  for (int off = 1; off < 64; off <<= 1) s += __shfl_xor(s, off);
  __shared__ float p1[4], p2[4];
  int wv = t >> 6, ln = t & 63;
  if (ln == 0) p1[wv] = s;
  __syncthreads();
  float mu = (p1[0] + p1[1] + p1[2] + p1[3]) * (1.0f / 1024.0f);
  float d0 = x4.x - mu, d1 = x4.y - mu, d2 = x4.z - mu, d3 = x4.w - mu;
  float q = d0 * d0 + d1 * d1 + d2 * d2 + d3 * d3;
#pragma unroll
  for (int off = 1; off < 64; off <<= 1) q += __shfl_xor(q, off);
  if (ln == 0) p2[wv] = q;
  __syncthreads();
  float var = (p2[0] + p2[1] + p2[2] + p2[3]) * (1.0f / 1024.0f);
  float rstd = rsqrtf(var + 1e-5f);
  float4 g4 = *(const float4*)(G + t * 4);
  float4 b4 = *(const float4*)(Bt + t * 4);
  float4 o4 = make_float4(d0 * rstd * g4.x + b4.x, d1 * rstd * g4.y + b4.y,
                          d2 * rstd * g4.z + b4.z, d3 * rstd * g4.w + b4.w);
  *(float4*)(O + (size_t)row * 1024 + t * 4) = o4;
}

// ---------------------------------------------------------------- GEMM fp32
// C[M,N] = A[M,K] @ B[K,N] (+bias) (+gelu) (+res). A has lda==K. B has ldb,
// C/res have ldc (for FFN column-chunk sub-panels). 128x128 tile, BK=8,
// 256 threads, 8x8 microtile. B-fragment split (tn*4 and 64+tn*4) keeps LDS
// reads <=2-way (free per m136).
__device__ __forceinline__ float gelu_f(float v) {
  return 0.5f * v * (1.0f + erff(v * 0.7071067811865475f));
}

template <int DO_BIAS, int DO_RES, int DO_GELU>
__global__ __launch_bounds__(256, 2) void gemm_f32(
    const float* __restrict__ A, const float* __restrict__ B,
    const float* __restrict__ bias, const float* __restrict__ res,
    float* __restrict__ C, int M, int N, int K, int ldb, int ldc) {
  __shared__ float As[8][128];  // [k][m]
  __shared__ float Bs[8][128];  // [k][n]
  int t = threadIdx.x;
  int bn = blockIdx.x, bm = blockIdx.y;
  int tm = t >> 4, tn = t & 15;
  int ar = t >> 1, ac = (t & 1) * 4;
  int kr = t >> 5, bc = (t & 31) * 4;
  const float* Ap = A + (size_t)(bm * 128 + ar) * K + ac;
  const float* Bp = B + (size_t)kr * ldb + bn * 128 + bc;
  float acc[8][8] = {};
  float4 av = *(const float4*)Ap;
  float4 bv = *(const float4*)Bp;
  for (int k0 = 0; k0 < K; k0 += 8) {
    As[ac + 0][ar] = av.x;
    As[ac + 1][ar] = av.y;
    As[ac + 2][ar] = av.z;
    As[ac + 3][ar] = av.w;
    *(float4*)&Bs[kr][bc] = bv;
    __syncthreads();
    if (k0 + 8 < K) {  // prefetch next k-slice while computing
      av = *(const float4*)(Ap + k0 + 8);
      bv = *(const float4*)(Bp + (size_t)(k0 + 8) * ldb);
    }
#pragma unroll
    for (int kk = 0; kk < 8; ++kk) {
      float a[8], b[8];
      *(float4*)&a[0] = *(const float4*)&As[kk][tm * 8];
      *(float4*)&a[4] = *(const float4*)&As[kk][tm * 8 + 4];
      *(float4*)&b[0] = *(const float4*)&Bs[kk][tn * 4];
      *(float4*)&b[4] = *(const float4*)&Bs[kk][64 + tn * 4];
#pragma unroll
      for (int i = 0; i < 8; ++i)
#pragma unroll
        for (int j = 0; j < 8; ++j) acc[i][j] = fmaf(a[i], b[j], acc[i][j]);
    }
    __syncthreads();
  }
  int col_a = bn * 128 + tn * 4, col_b = col_a + 64;
  float4 bias_a = make_float4(0, 0, 0, 0), bias_b = make_float4(0, 0, 0, 0);
  if (DO_BIAS) {
    bias_a = *(const float4*)&bias[col_a];
    bias_b = *(const float4*)&bias[col_b];
  }
#pragma unroll
  for (int i = 0; i < 8; ++i) {
    size_t ro = (size_t)(bm * 128 + tm * 8 + i) * ldc;
    float4 ca = make_float4(acc[i][0], acc[i][1], acc[i][2], acc[i][3]);
    float4 cb = make_float4(acc[i][4], acc[i][5], acc[i][6], acc[i][7]);
    if (DO_BIAS) {
      ca.x += bias_a.x; ca.y += bias_a.y; ca.z += bias_a.z; ca.w += bias_a.w;
      cb.x += bias_b.x; cb.y += bias_b.y; cb.z += bias_b.z; cb.w += bias_b.w;
    }
    if (DO_GELU) {
      ca.x = gelu_f(ca.x); ca.y = gelu_f(ca.y); ca.z = gelu_f(ca.z); ca.w = gelu_f(ca.w);
      cb.x = gelu_f(cb.x); cb.y = gelu_f(cb.y); cb.z = gelu_f(cb.z); cb.w = gelu_f(cb.w);
    }
    if (DO_RES) {
      float4 ra = *(const float4*)&res[ro + col_a];
      float4 rb = *(const float4*)&res[ro + col_b];
      ca.x += ra.x; ca.y += ra.y; ca.z += ra.z; ca.w += ra.w;
      cb.x += rb.x; cb.y += rb.y; cb.z += rb.z; cb.w += rb.w;
    }
    *(float4*)&C[ro + col_a] = ca;
    *(float4*)&C[ro + col_b] = cb;
  }
}

// ------------------------------------------------- V column-sum per (b,h)
// Rows whose every key is padding-masked: reference softmax degenerates to
// uniform over ALL S keys -> ctx = mean_s V.
__global__ __launch_bounds__(256) void vsum_k(const float* __restrict__ V,
                                              float* __restrict__ vsum) {
  int bh = blockIdx.x;
  int b = bh >> 4, hh = bh & 15;
  int t = threadIdx.x;
  int d = t & 63, sl = t >> 6;
  const int S = 2048, D = 1024;
  float acc = 0.0f;
  const float* base = V + (size_t)b * S * D + hh * 64 + d;
#pragma unroll 4
  for (int s5 = sl; s5 < S; s5 += 4) acc += base[(size_t)s5 * D];
  __shared__ float red[4][64];
  red[sl][d] = acc;
  __syncthreads();
  if (sl == 0) vsum[(size_t)bh * 64 + d] = red[0][d] + red[1][d] + red[2][d] + red[3][d];
}

// --------------------------------------------------------- Flash attention
// grid (S/64, H, B), 256 threads. Q/K transposed in LDS ([dk][row]) so inner
// reads are row-internal float4 (2-way banks = free). Online softmax in
// registers via 16-lane shfl row groups. Masked scores set to exactly -1e9
// (kept in the softmax, matching the reference).
__global__ __launch_bounds__(256, 2) void attn_f32(
    const float* __restrict__ Q, const float* __restrict__ Kg,
    const float* __restrict__ Vg, const int* __restrict__ amask,
    const float* __restrict__ vsum, float* __restrict__ ctx) {
  const int S = 2048, D = 1024;
  int qt = blockIdx.x, hh = blockIdx.y, b = blockIdx.z;
  int t = threadIdx.x;
  __shared__ float Qs[64][64];  // [dk][row], pre-scaled by 1/8
  __shared__ float Ks[64][64];  // [dk][row]
  __shared__ float Vs[64][64];  // [row][dk]
  __shared__ float Ps[64][64];  // [key][qrow]
  int wv = t >> 6, ln = t & 63;
  int lrow = (ln & 15) + 16 * wv;  // 0..63
  int lcol = (ln >> 4) * 4;        // 0,4,8,12
  {
    const float* qb = Q + (size_t)(b * S + qt * 64 + lrow) * D + hh * 64;
#pragma unroll
    for (int rep = 0; rep < 4; ++rep) {
      int dk = lcol + rep * 16;
      float4 v4 = *(const float4*)(qb + dk);
      Qs[dk + 0][lrow] = v4.x * 0.125f;
      Qs[dk + 1][lrow] = v4.y * 0.125f;
      Qs[dk + 2][lrow] = v4.z * 0.125f;
      Qs[dk + 3][lrow] = v4.w * 0.125f;
    }
  }
  int g = t >> 4, c = t & 15;
  int i0 = g * 4, j0 = c * 4, d0v = c * 4;
  float o[4][4] = {};
  float mrun[4] = {-INFINITY, -INFINITY, -INFINITY, -INFINITY};
  float lrun[4] = {};
  for (int kt = 0; kt <= qt; ++kt) {
    __syncthreads();  // prev phase4 done (and Qs visible on first iter)
    const float* kb = Kg + (size_t)(b * S + kt * 64 + lrow) * D + hh * 64;
    const float* vb = Vg + (size_t)(b * S + kt * 64 + lrow) * D + hh * 64;
#pragma unroll
    for (int rep = 0; rep < 4; ++rep) {
      int dk = lcol + rep * 16;
      float4 v4 = *(const float4*)(kb + dk);
      Ks[dk + 0][lrow] = v4.x;
      Ks[dk + 1][lrow] = v4.y;
      Ks[dk + 2][lrow] = v4.z;
      Ks[dk + 3][lrow] = v4.w;
      float4 w4 = *(const float4*)(vb + dk);
      *(float4*)&Vs[lrow][dk] = w4;
    }
    __syncthreads();
    // ---- phase 2: S = (Q/8) K^T, 4x4 per thread
    float sv[4][4] = {};
#pragma unroll 8
    for (int kk = 0; kk < 64; ++kk) {
      float a[4], bb[4];
      *(float4*)a = *(const float4*)&Qs[kk][i0];
      *(float4*)bb = *(const float4*)&Ks[kk][j0];
#pragma unroll
      for (int di = 0; di < 4; ++di)
#pragma unroll
        for (int dj = 0; dj < 4; ++dj)
          sv[di][dj] = fmaf(a[di], bb[dj], sv[di][dj]);
    }
    // ---- masks (causal + key padding), exactly NEG like the reference
    int4 mk = *(const int4*)&amask[b * S + kt * 64 + j0];
    int mks[4] = {mk.x, mk.y, mk.z, mk.w};
#pragma unroll
    for (int dj = 0; dj < 4; ++dj) {
      int jg = kt * 64 + j0 + dj;
#pragma unroll
      for (int di = 0; di < 4; ++di) {
        int ig = qt * 64 + i0 + di;
        if (mks[dj] == 0 || jg > ig) sv[di][dj] = NEGV;
      }
    }
    // ---- phase 3: online softmax in registers (16-lane row groups)
    float alpha[4];
#pragma unroll
    for (int di = 0; di < 4; ++di) {
      float mt = fmaxf(fmaxf(sv[di][0], sv[di][1]), fmaxf(sv[di][2], sv[di][3]));
#pragma unroll
      for (int off = 1; off < 16; off <<= 1) mt = fmaxf(mt, __shfl_xor(mt, off));
      float mn = fmaxf(mrun[di], mt);
      alpha[di] = expf(mrun[di] - mn);
      float rs = 0.0f;
#pragma unroll
      for (int dj = 0; dj < 4; ++dj) {
        float pv = expf(sv[di][dj] - mn);
        sv[di][dj] = pv;
        rs += pv;
      }
#pragma unroll
      for (int off = 1; off < 16; off <<= 1) rs += __shfl_xor(rs, off);
      lrun[di] = lrun[di] * alpha[di] + rs;
      mrun[di] = mn;
    }
#pragma unroll
    for (int dj = 0; dj < 4; ++dj) {
      float4 colv = make_float4(sv[0][dj], sv[1][dj], sv[2][dj], sv[3][dj]);
      *(float4*)&Ps[j0 + dj][i0] = colv;
    }
    __syncthreads();
    // ---- phase 4: O = alpha*O + P V
#pragma unroll
    for (int di = 0; di < 4; ++di) {
      float al = alpha[di];
#pragma unroll
      for (int dd = 0; dd < 4; ++dd) o[di][dd] *= al;
    }
#pragma unroll 8
    for (int jj = 0; jj < 64; ++jj) {
      float pa[4], va[4];
      *(float4*)pa = *(const float4*)&Ps[jj][i0];
      *(float4*)va = *(const float4*)&Vs[jj][d0v];
#pragma unroll
      for (int di = 0; di < 4; ++di)
#pragma unroll
        for (int dd = 0; dd < 4; ++dd)
          o[di][dd] = fmaf(pa[di], va[dd], o[di][dd]);
    }
  }
  // ---- epilogue: normalize; all-masked rows -> uniform over ALL S keys
#pragma unroll
  for (int di = 0; di < 4; ++di) {
    float inv = 1.0f / lrun[di];
    bool allm = (mrun[di] <= -1.0e8f);
    float4 ov;
    if (allm) {
      const float* vs = vsum + ((size_t)(b * 16 + hh) * 64) + d0v;
      ov = make_float4(vs[0] * (1.0f / 2048.0f), vs[1] * (1.0f / 2048.0f),
                       vs[2] * (1.0f / 2048.0f), vs[3] * (1.0f / 2048.0f));
    } else {
      ov = make_float4(o[di][0] * inv, o[di][1] * inv, o[di][2] * inv,
                       o[di][3] * inv);
    }
    *(float4*)&ctx[(size_t)(b * S + qt * 64 + i0 + di) * D + hh * 64 + d0v] = ov;
  }
}

// ============================================================================
extern "C" void kernel_launch(void* const* d_in, const int* in_sizes, int n_in,
                              void* d_out, int out_size, void* d_ws,
                              size_t ws_size, hipStream_t stream) {
  (void)in_sizes; (void)n_in; (void)out_size;
  const float* x   = (const float*)d_in[0];
  const int*   am  = (const int*)d_in[1];
  const float* Wq  = (const float*)d_in[2];
  const float* bq  = (const float*)d_in[3];
  const float* Wk  = (const float*)d_in[4];
  const float* bk  = (const float*)d_in[5];
  const float* Wv  = (const float*)d_in[6];
  const float* bv  = (const float*)d_in[7];
  const float* Wo  = (const float*)d_in[8];
  const float* bo  = (const float*)d_in[9];
  const float* W1  = (const float*)d_in[10];
  const float* b1  = (const float*)d_in[11];
  const float* W2  = (const float*)d_in[12];
  const float* b2  = (const float*)d_in[13];
  const float* g1  = (const float*)d_in[14];
  const float* be1 = (const float*)d_in[15];
  const float* g2  = (const float*)d_in[16];
  const float* be2 = (const float*)d_in[17];
  float* out = (float*)d_out;
  float* ws = (float*)d_ws;

  const size_t TD = 8192ull * 1024;  // one (B*S, D) fp32 buffer (32 MB)
  float* h    = ws;             // LN1 out; reused as ctx
  float* q    = ws + 1 * TD;    // reused as h2
  float* kbuf = ws + 2 * TD;
  float* vbuf = ws + 3 * TD;
  float* ctx  = h;
  float* h2   = q;
  float* fc   = ws + 2 * TD;    // FFN chunk buffer (k,v dead by then)
  float* x1   = out;            // attn residual lives in d_out (safe aliasing)
  float* vsm  = out;            // first 4096 floats; consumed before x1 write

  // FFN column-chunking sized to the workspace (branch is call-constant).
  const int chunk = (ws_size >= (6 * TD) * sizeof(float)) ? 4096 : 2048;

  ln_f32<<<8192, 256, 0, stream>>>(x, g1, be1, h);
  gemm_f32<1, 0, 0><<<dim3(8, 64), 256, 0, stream>>>(h, Wq, bq, nullptr, q, 8192, 1024, 1024, 1024, 1024);
  gemm_f32<1, 0, 0><<<dim3(8, 64), 256, 0, stream>>>(h, Wk, bk, nullptr, kbuf, 8192, 1024, 1024, 1024, 1024);
  gemm_f32<1, 0, 0><<<dim3(8, 64), 256, 0, stream>>>(h, Wv, bv, nullptr, vbuf, 8192, 1024, 1024, 1024, 1024);
  vsum_k<<<64, 256, 0, stream>>>(vbuf, vsm);
  attn_f32<<<dim3(32, 16, 4), 256, 0, stream>>>(q, kbuf, vbuf, am, vsm, ctx);
  gemm_f32<1, 1, 0><<<dim3(8, 64), 256, 0, stream>>>(ctx, Wo, bo, x, x1, 8192, 1024, 1024, 1024, 1024);
  ln_f32<<<8192, 256, 0, stream>>>(x1, g2, be2, h2);
  for (int p = 0; p * chunk < 4096; ++p) {
    const float* W1p = W1 + p * chunk;
    const float* b1p = b1 + p * chunk;
    const float* W2p = W2 + (size_t)p * chunk * 1024;
    gemm_f32<1, 0, 1><<<dim3(chunk / 128, 64), 256, 0, stream>>>(
        h2, W1p, b1p, nullptr, fc, 8192, chunk, 1024, 4096, chunk);
    if (p == 0) {
      gemm_f32<1, 1, 0><<<dim3(8, 64), 256, 0, stream>>>(
          fc, W2p, b2, x1, out, 8192, 1024, chunk, 1024, 1024);
    } else {
      gemm_f32<0, 1, 0><<<dim3(8, 64), 256, 0, stream>>>(
          fc, W2p, nullptr, out, out, 8192, 1024, chunk, 1024, 1024);
    }
  }
}

// Round 4
// 1742.479 us; speedup vs baseline: 2.2334x; 2.2334x over previous
//
#include <hip/hip_runtime.h>
#include <math.h>

// ============================================================================
// Transformer block, round 4: bf16 MFMA GEMMs + fp32 flash attention.
// B=4, S=2048, D=1024, H=16, dk=64, F=4096.
//
// Workspace plan (byte offsets, peak 120 MB; ws_size >= 128 MB guaranteed by
// round-3 pass):
//   0MB   WqT bf16 (2MB)   2MB WkT   4MB WvT   6MB WoT      [N x K transposed]
//   8MB   W1T bf16 (8MB)   16MB W2T bf16 (8MB)
//   24MB  h bf16 (16MB)    -> reused as ctx bf16
//   40MB  q f32 (32MB)     -> reused as h2 bf16 (16MB)
//   72MB  k f32 (32MB)     -> reused as fc bf16 chunk (32MB, chunk=2048)
//   104MB v bf16 (16MB)
//   120MB vsum f32 (16KB)
//   d_out: x1 (attn residual, f32) then final out (in-place res add, safe).
// ============================================================================

#define NEGV (-1.0e9f)

typedef short bfrag __attribute__((ext_vector_type(8)));   // 8 bf16 (4 VGPR)
typedef float ffrag __attribute__((ext_vector_type(4)));   // mfma f32x4 acc

__device__ __forceinline__ unsigned short f2bf(float f) {  // RNE f32->bf16
  unsigned u = __float_as_uint(f);
  u += 0x7fffu + ((u >> 16) & 1u);
  return (unsigned short)(u >> 16);
}
__device__ __forceinline__ float bf2f(unsigned short h) {
  return __uint_as_float(((unsigned)h) << 16);
}
__device__ __forceinline__ float gelu_f(float v) {
  return 0.5f * v * (1.0f + erff(v * 0.7071067811865475f));
}
__device__ __forceinline__ void gload16(const void* g, void* l) {
  __builtin_amdgcn_global_load_lds(
      (const __attribute__((address_space(1))) void*)g,
      (__attribute__((address_space(3))) void*)l, 16, 0, 0);
}

// ------------------------------------------- weight transpose+cast fp32->bf16
// src [R][C] f32  ->  dst [C][R] bf16
__global__ __launch_bounds__(256) void transpose_cast(
    const float* __restrict__ src, unsigned short* __restrict__ dst,
    int R, int C) {
  __shared__ float tile[32][33];
  int bx = blockIdx.x, by = blockIdx.y;
  int tx = threadIdx.x & 31, ty = threadIdx.x >> 5;
#pragma unroll
  for (int i = 0; i < 4; ++i)
    tile[ty + i * 8][tx] =
        src[(size_t)(by * 32 + ty + i * 8) * C + bx * 32 + tx];
  __syncthreads();
#pragma unroll
  for (int i = 0; i < 4; ++i)
    dst[(size_t)(bx * 32 + ty + i * 8) * R + by * 32 + tx] =
        f2bf(tile[tx][ty + i * 8]);
}

// ---------------------------------------------------------------- LayerNorm
// fp32 in -> bf16 out (feeds MFMA GEMM A-operand).
__global__ __launch_bounds__(256) void ln_bf16(
    const float* __restrict__ X, const float* __restrict__ G,
    const float* __restrict__ Bt, unsigned short* __restrict__ O) {
  int row = blockIdx.x, t = threadIdx.x;
  const float* xr = X + (size_t)row * 1024;
  float4 x4 = *(const float4*)(xr + t * 4);
  float s = x4.x + x4.y + x4.z + x4.w;
#pragma unroll
  for (int off = 1; off < 64; off <<= 1) s += __shfl_xor(s, off);
  __shared__ float p1[4], p2[4];
  int wv = t >> 6, ln = t & 63;
  if (ln == 0) p1[wv] = s;
  __syncthreads();
  float mu = (p1[0] + p1[1] + p1[2] + p1[3]) * (1.0f / 1024.0f);
  float d0 = x4.x - mu, d1 = x4.y - mu, d2 = x4.z - mu, d3 = x4.w - mu;
  float q = d0 * d0 + d1 * d1 + d2 * d2 + d3 * d3;
#pragma unroll
  for (int off = 1; off < 64; off <<= 1) q += __shfl_xor(q, off);
  if (ln == 0) p2[wv] = q;
  __syncthreads();
  float var = (p2[0] + p2[1] + p2[2] + p2[3]) * (1.0f / 1024.0f);
  float rstd = rsqrtf(var + 1e-5f);
  float4 g4 = *(const float4*)(G + t * 4);
  float4 b4 = *(const float4*)(Bt + t * 4);
  ushort4 o4;
  o4.x = f2bf(d0 * rstd * g4.x + b4.x);
  o4.y = f2bf(d1 * rstd * g4.y + b4.y);
  o4.z = f2bf(d2 * rstd * g4.z + b4.z);
  o4.w = f2bf(d3 * rstd * g4.w + b4.w);
  *(ushort4*)(O + (size_t)row * 1024 + t * 4) = o4;
}

// ---------------------------------------------------------------- MFMA GEMM
// C[M,N] = A[M,K](bf16) @ B[K,N] (+bias)(+gelu)(+res), B given as BT[N][ldbt].
// 128x128 tile, BK=64, 4 waves (2x2), 16x16x32 MFMA, 4x4 frags/wave.
// T2 XOR swizzle (16B unit ^= row&7) applied on BOTH global-source staging and
// ds_read (rule #21) -> <=2-way LDS conflicts. global_load_lds width 16.
template <int DO_BIAS, int DO_RES, int DO_GELU, int OUT_BF16>
__global__ __launch_bounds__(256) void gemm_bf16(
    const unsigned short* __restrict__ A, const unsigned short* __restrict__ BT,
    const float* __restrict__ bias, const float* __restrict__ res,
    void* __restrict__ Cv, int M, int N, int K, int lda, int ldbt, int ldc) {
  __shared__ short Asm[128 * 64];  // [row m][k], k-units XOR-swizzled
  __shared__ short Bsm[128 * 64];  // [row n][k]
  const int t = threadIdx.x;
  const int wv = t >> 6, lane = t & 63;
  const int wm = wv >> 1, wn = wv & 1;
  const int bn0 = blockIdx.x * 128, bm0 = blockIdx.y * 128;
  const int srow = t >> 3, sunit = t & 7;
  ffrag acc[4][4];
#pragma unroll
  for (int i = 0; i < 4; ++i)
#pragma unroll
    for (int j = 0; j < 4; ++j) acc[i][j] = {0.f, 0.f, 0.f, 0.f};

  for (int kk = 0; kk < K; kk += 64) {
#pragma unroll
    for (int i = 0; i < 4; ++i) {  // stage A: 4 x (256 lanes x 16B) = 16KB
      int row = i * 32 + srow;
      int su = sunit ^ (row & 7);  // inverse-swizzled global source
      gload16(A + (size_t)(bm0 + row) * lda + kk + su * 8,
              Asm + i * 2048 + wv * 512);
    }
#pragma unroll
    for (int i = 0; i < 4; ++i) {  // stage B^T
      int row = i * 32 + srow;
      int su = sunit ^ (row & 7);
      gload16(BT + (size_t)(bn0 + row) * ldbt + kk + su * 8,
              Bsm + i * 2048 + wv * 512);
    }
    asm volatile("s_waitcnt vmcnt(0)" ::: "memory");
    __syncthreads();
#pragma unroll
    for (int kh = 0; kh < 2; ++kh) {
      bfrag af[4], bf[4];
#pragma unroll
      for (int mi = 0; mi < 4; ++mi) {
        int row = wm * 64 + mi * 16 + (lane & 15);
        int u = (kh * 4 + (lane >> 4)) ^ (row & 7);  // swizzled read
        af[mi] = *(const bfrag*)&Asm[row * 64 + u * 8];
      }
#pragma unroll
      for (int ni = 0; ni < 4; ++ni) {
        int row = wn * 64 + ni * 16 + (lane & 15);
        int u = (kh * 4 + (lane >> 4)) ^ (row & 7);
        bf[ni] = *(const bfrag*)&Bsm[row * 64 + u * 8];
      }
#pragma unroll
      for (int mi = 0; mi < 4; ++mi)
#pragma unroll
        for (int ni = 0; ni < 4; ++ni)
          acc[mi][ni] = __builtin_amdgcn_mfma_f32_16x16x32_bf16(
              af[mi], bf[ni], acc[mi][ni], 0, 0, 0);
    }
    __syncthreads();
  }
  // epilogue: C/D frag mapping col=lane&15, row=(lane>>4)*4+reg (m89-verified)
  const int crow0 = bm0 + wm * 64 + (lane >> 4) * 4;
  const int ccol0 = bn0 + wn * 64 + (lane & 15);
#pragma unroll
  for (int ni = 0; ni < 4; ++ni) {
    int col = ccol0 + ni * 16;
    float bi = DO_BIAS ? bias[col] : 0.0f;
#pragma unroll
    for (int mi = 0; mi < 4; ++mi) {
#pragma unroll
      for (int r = 0; r < 4; ++r) {
        int row = crow0 + mi * 16 + r;
        float v = acc[mi][ni][r] + bi;
        if (DO_GELU) v = gelu_f(v);
        if (DO_RES) v += res[(size_t)row * ldc + col];
        if (OUT_BF16)
          ((unsigned short*)Cv)[(size_t)row * ldc + col] = f2bf(v);
        else
          ((float*)Cv)[(size_t)row * ldc + col] = v;
      }
    }
  }
}

// ------------------------------------------------- V column-sum per (b,h)
__global__ __launch_bounds__(256) void vsum_k(
    const unsigned short* __restrict__ V, float* __restrict__ vsum) {
  int bh = blockIdx.x;
  int b = bh >> 4, hh = bh & 15;
  int t = threadIdx.x;
  int d = t & 63, sl = t >> 6;
  const int S = 2048, D = 1024;
  float acc = 0.0f;
  const unsigned short* base = V + (size_t)b * S * D + hh * 64 + d;
#pragma unroll 4
  for (int s5 = sl; s5 < S; s5 += 4) acc += bf2f(base[(size_t)s5 * D]);
  __shared__ float red[4][64];
  red[sl][d] = acc;
  __syncthreads();
  if (sl == 0)
    vsum[(size_t)bh * 64 + d] = red[0][d] + red[1][d] + red[2][d] + red[3][d];
}

// --------------------------------------------------------- Flash attention
// q,k fp32; V bf16; ctx out bf16. Internals unchanged from the passing
// round-3 kernel (fp32 compute, online softmax, exact -1e9 mask semantics,
// degenerate all-masked rows -> vsum/2048).
__global__ __launch_bounds__(256, 2) void attn_f32(
    const float* __restrict__ Q, const float* __restrict__ Kg,
    const unsigned short* __restrict__ Vg, const int* __restrict__ amask,
    const float* __restrict__ vsum, unsigned short* __restrict__ ctx) {
  const int S = 2048, D = 1024;
  int qt = blockIdx.x, hh = blockIdx.y, b = blockIdx.z;
  int t = threadIdx.x;
  __shared__ float Qs[64][64];  // [dk][row], pre-scaled by 1/8
  __shared__ float Ks[64][64];  // [dk][row]
  __shared__ float Vs[64][64];  // [row][dk]
  __shared__ float Ps[64][64];  // [key][qrow]
  int wv = t >> 6, ln = t & 63;
  int lrow = (ln & 15) + 16 * wv;
  int lcol = (ln >> 4) * 4;
  {
    const float* qb = Q + (size_t)(b * S + qt * 64 + lrow) * D + hh * 64;
#pragma unroll
    for (int rep = 0; rep < 4; ++rep) {
      int dk = lcol + rep * 16;
      float4 v4 = *(const float4*)(qb + dk);
      Qs[dk + 0][lrow] = v4.x * 0.125f;
      Qs[dk + 1][lrow] = v4.y * 0.125f;
      Qs[dk + 2][lrow] = v4.z * 0.125f;
      Qs[dk + 3][lrow] = v4.w * 0.125f;
    }
  }
  int g = t >> 4, c = t & 15;
  int i0 = g * 4, j0 = c * 4, d0v = c * 4;
  float o[4][4] = {};
  float mrun[4] = {-INFINITY, -INFINITY, -INFINITY, -INFINITY};
  float lrun[4] = {};
  for (int kt = 0; kt <= qt; ++kt) {
    __syncthreads();
    const float* kb = Kg + (size_t)(b * S + kt * 64 + lrow) * D + hh * 64;
    const unsigned short* vb =
        Vg + (size_t)(b * S + kt * 64 + lrow) * D + hh * 64;
#pragma unroll
    for (int rep = 0; rep < 4; ++rep) {
      int dk = lcol + rep * 16;
      float4 v4 = *(const float4*)(kb + dk);
      Ks[dk + 0][lrow] = v4.x;
      Ks[dk + 1][lrow] = v4.y;
      Ks[dk + 2][lrow] = v4.z;
      Ks[dk + 3][lrow] = v4.w;
      ushort4 w4 = *(const ushort4*)(vb + dk);
      *(float4*)&Vs[lrow][dk] =
          make_float4(bf2f(w4.x), bf2f(w4.y), bf2f(w4.z), bf2f(w4.w));
    }
    __syncthreads();
    float sv[4][4] = {};
#pragma unroll 8
    for (int kk = 0; kk < 64; ++kk) {
      float a[4], bb[4];
      *(float4*)a = *(const float4*)&Qs[kk][i0];
      *(float4*)bb = *(const float4*)&Ks[kk][j0];
#pragma unroll
      for (int di = 0; di < 4; ++di)
#pragma unroll
        for (int dj = 0; dj < 4; ++dj)
          sv[di][dj] = fmaf(a[di], bb[dj], sv[di][dj]);
    }
    int4 mk = *(const int4*)&amask[b * S + kt * 64 + j0];
    int mks[4] = {mk.x, mk.y, mk.z, mk.w};
#pragma unroll
    for (int dj = 0; dj < 4; ++dj) {
      int jg = kt * 64 + j0 + dj;
#pragma unroll
      for (int di = 0; di < 4; ++di) {
        int ig = qt * 64 + i0 + di;
        if (mks[dj] == 0 || jg > ig) sv[di][dj] = NEGV;
      }
    }
    float alpha[4];
#pragma unroll
    for (int di = 0; di < 4; ++di) {
      float mt = fmaxf(fmaxf(sv[di][0], sv[di][1]), fmaxf(sv[di][2], sv[di][3]));
#pragma unroll
      for (int off = 1; off < 16; off <<= 1) mt = fmaxf(mt, __shfl_xor(mt, off));
      float mn = fmaxf(mrun[di], mt);
      alpha[di] = expf(mrun[di] - mn);
      float rs = 0.0f;
#pragma unroll
      for (int dj = 0; dj < 4; ++dj) {
        float pv = expf(sv[di][dj] - mn);
        sv[di][dj] = pv;
        rs += pv;
      }
#pragma unroll
      for (int off = 1; off < 16; off <<= 1) rs += __shfl_xor(rs, off);
      lrun[di] = lrun[di] * alpha[di] + rs;
      mrun[di] = mn;
    }
#pragma unroll
    for (int dj = 0; dj < 4; ++dj) {
      float4 colv = make_float4(sv[0][dj], sv[1][dj], sv[2][dj], sv[3][dj]);
      *(float4*)&Ps[j0 + dj][i0] = colv;
    }
    __syncthreads();
#pragma unroll
    for (int di = 0; di < 4; ++di) {
      float al = alpha[di];
#pragma unroll
      for (int dd = 0; dd < 4; ++dd) o[di][dd] *= al;
    }
#pragma unroll 8
    for (int jj = 0; jj < 64; ++jj) {
      float pa[4], va[4];
      *(float4*)pa = *(const float4*)&Ps[jj][i0];
      *(float4*)va = *(const float4*)&Vs[jj][d0v];
#pragma unroll
      for (int di = 0; di < 4; ++di)
#pragma unroll
        for (int dd = 0; dd < 4; ++dd)
          o[di][dd] = fmaf(pa[di], va[dd], o[di][dd]);
    }
  }
#pragma unroll
  for (int di = 0; di < 4; ++di) {
    float inv = 1.0f / lrun[di];
    bool allm = (mrun[di] <= -1.0e8f);
    float4 ov;
    if (allm) {
      const float* vs = vsum + ((size_t)(b * 16 + hh) * 64) + d0v;
      ov = make_float4(vs[0] * (1.0f / 2048.0f), vs[1] * (1.0f / 2048.0f),
                       vs[2] * (1.0f / 2048.0f), vs[3] * (1.0f / 2048.0f));
    } else {
      ov = make_float4(o[di][0] * inv, o[di][1] * inv, o[di][2] * inv,
                       o[di][3] * inv);
    }
    ushort4 ob;
    ob.x = f2bf(ov.x); ob.y = f2bf(ov.y); ob.z = f2bf(ov.z); ob.w = f2bf(ov.w);
    *(ushort4*)&ctx[(size_t)(b * S + qt * 64 + i0 + di) * D + hh * 64 + d0v] = ob;
  }
}

// ============================================================================
extern "C" void kernel_launch(void* const* d_in, const int* in_sizes, int n_in,
                              void* d_out, int out_size, void* d_ws,
                              size_t ws_size, hipStream_t stream) {
  (void)in_sizes; (void)n_in; (void)out_size; (void)ws_size;
  const float* x   = (const float*)d_in[0];
  const int*   am  = (const int*)d_in[1];
  const float* Wq  = (const float*)d_in[2];
  const float* bq  = (const float*)d_in[3];
  const float* Wk  = (const float*)d_in[4];
  const float* bk  = (const float*)d_in[5];
  const float* Wv  = (const float*)d_in[6];
  const float* bv  = (const float*)d_in[7];
  const float* Wo  = (const float*)d_in[8];
  const float* bo  = (const float*)d_in[9];
  const float* W1  = (const float*)d_in[10];
  const float* b1  = (const float*)d_in[11];
  const float* W2  = (const float*)d_in[12];
  const float* b2  = (const float*)d_in[13];
  const float* g1  = (const float*)d_in[14];
  const float* be1 = (const float*)d_in[15];
  const float* g2  = (const float*)d_in[16];
  const float* be2 = (const float*)d_in[17];
  float* out = (float*)d_out;

  unsigned char* w8 = (unsigned char*)d_ws;
  const size_t MB = 1024ull * 1024;
  unsigned short* WqT = (unsigned short*)(w8 + 0 * MB);
  unsigned short* WkT = (unsigned short*)(w8 + 2 * MB);
  unsigned short* WvT = (unsigned short*)(w8 + 4 * MB);
  unsigned short* WoT = (unsigned short*)(w8 + 6 * MB);
  unsigned short* W1T = (unsigned short*)(w8 + 8 * MB);
  unsigned short* W2T = (unsigned short*)(w8 + 16 * MB);
  unsigned short* h   = (unsigned short*)(w8 + 24 * MB);  // -> ctx
  float*          q   = (float*)(w8 + 40 * MB);           // -> h2
  float*          kb  = (float*)(w8 + 72 * MB);           // -> fc
  unsigned short* v   = (unsigned short*)(w8 + 104 * MB);
  float*          vsm = (float*)(w8 + 120 * MB);
  unsigned short* ctx = h;
  unsigned short* h2  = (unsigned short*)(w8 + 40 * MB);
  unsigned short* fc  = (unsigned short*)(w8 + 72 * MB);
  float*          x1  = out;

  // Weights -> bf16 transposed (N x K), every call (re-poison safe).
  transpose_cast<<<dim3(32, 32), 256, 0, stream>>>(Wq, WqT, 1024, 1024);
  transpose_cast<<<dim3(32, 32), 256, 0, stream>>>(Wk, WkT, 1024, 1024);
  transpose_cast<<<dim3(32, 32), 256, 0, stream>>>(Wv, WvT, 1024, 1024);
  transpose_cast<<<dim3(32, 32), 256, 0, stream>>>(Wo, WoT, 1024, 1024);
  transpose_cast<<<dim3(128, 32), 256, 0, stream>>>(W1, W1T, 1024, 4096);
  transpose_cast<<<dim3(32, 128), 256, 0, stream>>>(W2, W2T, 4096, 1024);

  ln_bf16<<<8192, 256, 0, stream>>>(x, g1, be1, h);
  gemm_bf16<1, 0, 0, 0><<<dim3(8, 64), 256, 0, stream>>>(
      h, WqT, bq, nullptr, q, 8192, 1024, 1024, 1024, 1024, 1024);
  gemm_bf16<1, 0, 0, 0><<<dim3(8, 64), 256, 0, stream>>>(
      h, WkT, bk, nullptr, kb, 8192, 1024, 1024, 1024, 1024, 1024);
  gemm_bf16<1, 0, 0, 1><<<dim3(8, 64), 256, 0, stream>>>(
      h, WvT, bv, nullptr, v, 8192, 1024, 1024, 1024, 1024, 1024);
  vsum_k<<<64, 256, 0, stream>>>(v, vsm);
  attn_f32<<<dim3(32, 16, 4), 256, 0, stream>>>(q, kb, v, am, vsm, ctx);
  gemm_bf16<1, 1, 0, 0><<<dim3(8, 64), 256, 0, stream>>>(
      ctx, WoT, bo, x, x1, 8192, 1024, 1024, 1024, 1024, 1024);
  ln_bf16<<<8192, 256, 0, stream>>>(x1, g2, be2, h2);
  for (int p = 0; p < 2; ++p) {  // FFN in two 2048-wide chunks
    gemm_bf16<1, 0, 1, 1><<<dim3(16, 64), 256, 0, stream>>>(
        h2, W1T + (size_t)p * 2048 * 1024, b1 + p * 2048, nullptr, fc,
        8192, 2048, 1024, 1024, 1024, 2048);
    if (p == 0) {
      gemm_bf16<1, 1, 0, 0><<<dim3(8, 64), 256, 0, stream>>>(
          fc, W2T + p * 2048, b2, x1, out, 8192, 1024, 2048, 2048, 4096, 1024);
    } else {
      gemm_bf16<0, 1, 0, 0><<<dim3(8, 64), 256, 0, stream>>>(
          fc, W2T + p * 2048, nullptr, out, out, 8192, 1024, 2048, 2048, 4096, 1024);
    }
  }
}

// Round 8
// 795.552 us; speedup vs baseline: 4.8919x; 2.1903x over previous
//
#include <hip/hip_runtime.h>
#include <math.h>

// ============================================================================
// Transformer block, round 8: verbatim resubmission of round-5/6/7 source
// (three consecutive GPU-acquisition timeouts; kernel has never executed).
// bf16 MFMA GEMMs + bf16 MFMA flash attention.
// B=4, S=2048, D=1024, H=16, dk=64, F=4096.
//
// Workspace (byte offsets, peak 120 MB + 16 KB):
//   0 WqT 2 WkT 4 WvT 6 WoT 8 W1T(8) 16 W2T(8)        [bf16, N x K]
//   24 h bf16(16)  -> ctx bf16
//   40 q bf16(16)  -> h2 bf16
//   56 k bf16(16)  -> fc bf16 (32, FFN chunk 2048)
//   88 v bf16(16)  (row-major, dead after vtrans; fc ends at 88)
//   104 vT bf16(16) [bh][d][s]
//   120 vsum f32 (16 KB)
//   d_out: x1 (attn residual f32), then final out (in-place res add, safe).
// ============================================================================

#define NEGV (-1.0e9f)

typedef short bfrag __attribute__((ext_vector_type(8)));   // 8 bf16 (4 VGPR)
typedef float ffrag __attribute__((ext_vector_type(4)));   // mfma f32x4 acc
typedef unsigned short usvec8 __attribute__((ext_vector_type(8)));

__device__ __forceinline__ unsigned short f2bf(float f) {  // RNE f32->bf16
  unsigned u = __float_as_uint(f);
  u += 0x7fffu + ((u >> 16) & 1u);
  return (unsigned short)(u >> 16);
}
__device__ __forceinline__ float bf2f(unsigned short h) {
  return __uint_as_float(((unsigned)h) << 16);
}
__device__ __forceinline__ float gelu_f(float v) {
  return 0.5f * v * (1.0f + erff(v * 0.7071067811865475f));
}
__device__ __forceinline__ void gload16(const void* g, void* l) {
  __builtin_amdgcn_global_load_lds(
      (const __attribute__((address_space(1))) void*)g,
      (__attribute__((address_space(3))) void*)l, 16, 0, 0);
}

// ------------------------------------------- weight transpose+cast fp32->bf16
__global__ __launch_bounds__(256) void transpose_cast(
    const float* __restrict__ src, unsigned short* __restrict__ dst,
    int R, int C) {
  __shared__ float tile[32][33];
  int bx = blockIdx.x, by = blockIdx.y;
  int tx = threadIdx.x & 31, ty = threadIdx.x >> 5;
#pragma unroll
  for (int i = 0; i < 4; ++i)
    tile[ty + i * 8][tx] =
        src[(size_t)(by * 32 + ty + i * 8) * C + bx * 32 + tx];
  __syncthreads();
#pragma unroll
  for (int i = 0; i < 4; ++i)
    dst[(size_t)(bx * 32 + ty + i * 8) * R + by * 32 + tx] =
        f2bf(tile[tx][ty + i * 8]);
}

// ---------------------------------------------------------------- LayerNorm
__global__ __launch_bounds__(256) void ln_bf16(
    const float* __restrict__ X, const float* __restrict__ G,
    const float* __restrict__ Bt, unsigned short* __restrict__ O) {
  int row = blockIdx.x, t = threadIdx.x;
  const float* xr = X + (size_t)row * 1024;
  float4 x4 = *(const float4*)(xr + t * 4);
  float s = x4.x + x4.y + x4.z + x4.w;
#pragma unroll
  for (int off = 1; off < 64; off <<= 1) s += __shfl_xor(s, off);
  __shared__ float p1[4], p2[4];
  int wv = t >> 6, ln = t & 63;
  if (ln == 0) p1[wv] = s;
  __syncthreads();
  float mu = (p1[0] + p1[1] + p1[2] + p1[3]) * (1.0f / 1024.0f);
  float d0 = x4.x - mu, d1 = x4.y - mu, d2 = x4.z - mu, d3 = x4.w - mu;
  float q = d0 * d0 + d1 * d1 + d2 * d2 + d3 * d3;
#pragma unroll
  for (int off = 1; off < 64; off <<= 1) q += __shfl_xor(q, off);
  if (ln == 0) p2[wv] = q;
  __syncthreads();
  float var = (p2[0] + p2[1] + p2[2] + p2[3]) * (1.0f / 1024.0f);
  float rstd = rsqrtf(var + 1e-5f);
  float4 g4 = *(const float4*)(G + t * 4);
  float4 b4 = *(const float4*)(Bt + t * 4);
  ushort4 o4;
  o4.x = f2bf(d0 * rstd * g4.x + b4.x);
  o4.y = f2bf(d1 * rstd * g4.y + b4.y);
  o4.z = f2bf(d2 * rstd * g4.z + b4.z);
  o4.w = f2bf(d3 * rstd * g4.w + b4.w);
  *(ushort4*)(O + (size_t)row * 1024 + t * 4) = o4;
}

// ---------------------------------------------------------------- MFMA GEMM
// (unchanged from round 4, verified on HW) C = A(bf16) @ BT^T (+bias)(+gelu)(+res).
template <int DO_BIAS, int DO_RES, int DO_GELU, int OUT_BF16>
__global__ __launch_bounds__(256) void gemm_bf16(
    const unsigned short* __restrict__ A, const unsigned short* __restrict__ BT,
    const float* __restrict__ bias, const float* __restrict__ res,
    void* __restrict__ Cv, int M, int N, int K, int lda, int ldbt, int ldc) {
  __shared__ short Asm[128 * 64];
  __shared__ short Bsm[128 * 64];
  const int t = threadIdx.x;
  const int wv = t >> 6, lane = t & 63;
  const int wm = wv >> 1, wn = wv & 1;
  const int bn0 = blockIdx.x * 128, bm0 = blockIdx.y * 128;
  const int srow = t >> 3, sunit = t & 7;
  ffrag acc[4][4];
#pragma unroll
  for (int i = 0; i < 4; ++i)
#pragma unroll
    for (int j = 0; j < 4; ++j) acc[i][j] = {0.f, 0.f, 0.f, 0.f};

  for (int kk = 0; kk < K; kk += 64) {
#pragma unroll
    for (int i = 0; i < 4; ++i) {
      int row = i * 32 + srow;
      int su = sunit ^ (row & 7);
      gload16(A + (size_t)(bm0 + row) * lda + kk + su * 8,
              Asm + i * 2048 + wv * 512);
    }
#pragma unroll
    for (int i = 0; i < 4; ++i) {
      int row = i * 32 + srow;
      int su = sunit ^ (row & 7);
      gload16(BT + (size_t)(bn0 + row) * ldbt + kk + su * 8,
              Bsm + i * 2048 + wv * 512);
    }
    asm volatile("s_waitcnt vmcnt(0)" ::: "memory");
    __syncthreads();
#pragma unroll
    for (int kh = 0; kh < 2; ++kh) {
      bfrag af[4], bf[4];
#pragma unroll
      for (int mi = 0; mi < 4; ++mi) {
        int row = wm * 64 + mi * 16 + (lane & 15);
        int u = (kh * 4 + (lane >> 4)) ^ (row & 7);
        af[mi] = *(const bfrag*)&Asm[row * 64 + u * 8];
      }
#pragma unroll
      for (int ni = 0; ni < 4; ++ni) {
        int row = wn * 64 + ni * 16 + (lane & 15);
        int u = (kh * 4 + (lane >> 4)) ^ (row & 7);
        bf[ni] = *(const bfrag*)&Bsm[row * 64 + u * 8];
      }
#pragma unroll
      for (int mi = 0; mi < 4; ++mi)
#pragma unroll
        for (int ni = 0; ni < 4; ++ni)
          acc[mi][ni] = __builtin_amdgcn_mfma_f32_16x16x32_bf16(
              af[mi], bf[ni], acc[mi][ni], 0, 0, 0);
    }
    __syncthreads();
  }
  const int crow0 = bm0 + wm * 64 + (lane >> 4) * 4;
  const int ccol0 = bn0 + wn * 64 + (lane & 15);
#pragma unroll
  for (int ni = 0; ni < 4; ++ni) {
    int col = ccol0 + ni * 16;
    float bi = DO_BIAS ? bias[col] : 0.0f;
#pragma unroll
    for (int mi = 0; mi < 4; ++mi) {
#pragma unroll
      for (int r = 0; r < 4; ++r) {
        int row = crow0 + mi * 16 + r;
        float v = acc[mi][ni][r] + bi;
        if (DO_GELU) v = gelu_f(v);
        if (DO_RES) v += res[(size_t)row * ldc + col];
        if (OUT_BF16)
          ((unsigned short*)Cv)[(size_t)row * ldc + col] = f2bf(v);
        else
          ((float*)Cv)[(size_t)row * ldc + col] = v;
      }
    }
  }
}

// --------------------------------------------- V [token][1024] -> vT[bh][d][s]
__global__ __launch_bounds__(256) void vtrans(
    const unsigned short* __restrict__ V, unsigned short* __restrict__ VT) {
  __shared__ unsigned short tile[64 * 65];  // [d][s], odd stride
  int st = blockIdx.x, bh = blockIdx.y;
  int b = bh >> 4, hh = bh & 15;
  int t = threadIdx.x;
  int s0 = st * 64;
  int sr = t >> 3, u = t & 7;
#pragma unroll
  for (int p = 0; p < 2; ++p) {
    int s = p * 32 + sr;
    usvec8 vv = *(const usvec8*)(V + (size_t)(b * 2048 + s0 + s) * 1024 +
                                 hh * 64 + u * 8);
#pragma unroll
    for (int j = 0; j < 8; ++j) tile[(u * 8 + j) * 65 + s] = vv[j];
  }
  __syncthreads();
  int dr = t >> 2, c = t & 3;
#pragma unroll
  for (int p = 0; p < 2; ++p) {
    int su = p * 4 + c;
    usvec8 ov;
#pragma unroll
    for (int j = 0; j < 8; ++j) ov[j] = tile[dr * 65 + su * 8 + j];
    *(usvec8*)(VT + (size_t)bh * 64 * 2048 + (size_t)dr * 2048 + s0 + su * 8) =
        ov;
  }
}

// ------------------------------------------------- V column-sum from vT
__global__ __launch_bounds__(256) void vsum_k(
    const unsigned short* __restrict__ VT, float* __restrict__ vsum) {
  int bh = blockIdx.x;
  int t = threadIdx.x;
  int d = t >> 2, c = t & 3;
  const unsigned short* row = VT + (size_t)bh * 131072 + (size_t)d * 2048;
  float acc = 0.0f;
#pragma unroll 4
  for (int i = 0; i < 64; ++i) {
    usvec8 vv = *(const usvec8*)(row + c * 8 + i * 32);
#pragma unroll
    for (int j = 0; j < 8; ++j) acc += bf2f(vv[j]);
  }
  acc += __shfl_xor(acc, 1);
  acc += __shfl_xor(acc, 2);
  if (c == 0) vsum[bh * 64 + d] = acc;
}

// --------------------------------------------------- MFMA flash attention
// grid (S/64, H, B), 256 threads = 4 waves; wave w owns q rows w*16..w*16+15.
// Frag conventions identical to gemm_bf16 (HW-verified): A row=lane&15, 8
// consecutive k per lane (kgrp=lane>>4); D col=lane&15, row=(lane>>4)*4+reg.
// All LDS tiles linear [64][64] bf16 with 16B-unit XOR swizzle (u ^= row&7),
// staged via global_load_lds from pre-swizzled global source (rule #21).
__global__ __launch_bounds__(256) void attn_mfma(
    const unsigned short* __restrict__ Qg, const unsigned short* __restrict__ Kg,
    const unsigned short* __restrict__ VT, const int* __restrict__ amask,
    const float* __restrict__ vsum, unsigned short* __restrict__ ctx) {
  const int S = 2048, D = 1024;
  int qt = blockIdx.x, hh = blockIdx.y, b = blockIdx.z;
  int t = threadIdx.x;
  int wv = t >> 6, lane = t & 63;
  int l15 = lane & 15, l4 = lane >> 4;
  __shared__ short Qs[64 * 64];
  __shared__ short Ks[64 * 64];
  __shared__ short Vs[64 * 64];   // vT tile: [d][kpos]
  __shared__ short Ps[4][16 * 64];
  const int srow = t >> 3, sunit = t & 7;

  // stage Q tile once (rows q, cols d of head hh)
  {
    const unsigned short* qb = Qg + (size_t)(b * S + qt * 64) * D + hh * 64;
#pragma unroll
    for (int i = 0; i < 2; ++i) {
      int row = i * 32 + srow;
      int su = sunit ^ (row & 7);
      gload16(qb + (size_t)row * D + su * 8, Qs + i * 2048 + wv * 512);
    }
  }

  ffrag o[4];
#pragma unroll
  for (int ni = 0; ni < 4; ++ni) o[ni] = {0.f, 0.f, 0.f, 0.f};
  float mrun[4] = {-INFINITY, -INFINITY, -INFINITY, -INFINITY};
  float lrun[4] = {0.f, 0.f, 0.f, 0.f};

  const unsigned short* kbase = Kg + (size_t)b * S * D + hh * 64;
  const unsigned short* vtb = VT + (size_t)(b * 16 + hh) * 64 * 2048;
  const int qrow0 = qt * 64 + wv * 16 + l4 * 4;

  for (int kt = 0; kt <= qt; ++kt) {
    __syncthreads();  // all waves done reading prev Ks/Vs
#pragma unroll
    for (int i = 0; i < 2; ++i) {  // stage K tile [kpos][d]
      int row = i * 32 + srow;
      int su = sunit ^ (row & 7);
      gload16(kbase + (size_t)(kt * 64 + row) * D + su * 8,
              Ks + i * 2048 + wv * 512);
    }
#pragma unroll
    for (int i = 0; i < 2; ++i) {  // stage vT tile [d][kpos]
      int row = i * 32 + srow;
      int su = sunit ^ (row & 7);
      gload16(vtb + (size_t)row * 2048 + kt * 64 + su * 8,
              Vs + i * 2048 + wv * 512);
    }
    asm volatile("s_waitcnt vmcnt(0)" ::: "memory");
    __syncthreads();

    // ---- QK^T: S[16q][64kpos] per wave
    bfrag aq[2];
#pragma unroll
    for (int kh = 0; kh < 2; ++kh) {
      int row = wv * 16 + l15;
      int u = (kh * 4 + l4) ^ (row & 7);
      aq[kh] = *(const bfrag*)&Qs[row * 64 + u * 8];
    }
    float sv[4][4];  // [ni kpos-chunk][reg row]
#pragma unroll
    for (int ni = 0; ni < 4; ++ni) {
      ffrag sf = {0.f, 0.f, 0.f, 0.f};
#pragma unroll
      for (int kh = 0; kh < 2; ++kh) {
        int row = ni * 16 + l15;
        int u = (kh * 4 + l4) ^ (row & 7);
        bfrag bk = *(const bfrag*)&Ks[row * 64 + u * 8];
        sf = __builtin_amdgcn_mfma_f32_16x16x32_bf16(aq[kh], bk, sf, 0, 0, 0);
      }
#pragma unroll
      for (int r = 0; r < 4; ++r) sv[ni][r] = sf[r] * 0.125f;
    }
    // ---- masks (causal + key padding), exactly -1e9
#pragma unroll
    for (int ni = 0; ni < 4; ++ni) {
      int kpos = kt * 64 + ni * 16 + l15;
      int mk = amask[b * S + kpos];
#pragma unroll
      for (int r = 0; r < 4; ++r)
        if (mk == 0 || kpos > qrow0 + r) sv[ni][r] = NEGV;
    }
    // ---- online softmax (16-lane row groups; frag rows match m/l ownership)
    float alpha[4];
#pragma unroll
    for (int r = 0; r < 4; ++r) {
      float mt = fmaxf(fmaxf(sv[0][r], sv[1][r]), fmaxf(sv[2][r], sv[3][r]));
#pragma unroll
      for (int off = 1; off < 16; off <<= 1) mt = fmaxf(mt, __shfl_xor(mt, off));
      float mn = fmaxf(mrun[r], mt);
      alpha[r] = expf(mrun[r] - mn);
      float rs = 0.0f;
#pragma unroll
      for (int ni = 0; ni < 4; ++ni) {
        float pv = expf(sv[ni][r] - mn);
        sv[ni][r] = pv;
        rs += pv;
      }
#pragma unroll
      for (int off = 1; off < 16; off <<= 1) rs += __shfl_xor(rs, off);
      lrun[r] = lrun[r] * alpha[r] + rs;
      mrun[r] = mn;
    }
    // ---- P -> LDS bf16 (per-wave, swizzled)
#pragma unroll
    for (int ni = 0; ni < 4; ++ni) {
      int cu = ni * 2 + (l15 >> 3);
#pragma unroll
      for (int r = 0; r < 4; ++r) {
        int row = l4 * 4 + r;
        int su = cu ^ (row & 7);
        Ps[wv][row * 64 + su * 8 + (l15 & 7)] = f2bf(sv[ni][r]);
      }
    }
    // ---- PV: O[16q][64d] += P[16q][64kpos] * vT[d][kpos]^T
#pragma unroll
    for (int ni = 0; ni < 4; ++ni)
#pragma unroll
      for (int r = 0; r < 4; ++r) o[ni][r] *= alpha[r];
    bfrag pa[2];
#pragma unroll
    for (int kh = 0; kh < 2; ++kh) {
      int row = l15;
      int u = (kh * 4 + l4) ^ (row & 7);
      pa[kh] = *(const bfrag*)&Ps[wv][row * 64 + u * 8];
    }
#pragma unroll
    for (int ni = 0; ni < 4; ++ni) {
#pragma unroll
      for (int kh = 0; kh < 2; ++kh) {
        int drow = ni * 16 + l15;
        int u = (kh * 4 + l4) ^ (drow & 7);
        bfrag bv = *(const bfrag*)&Vs[drow * 64 + u * 8];
        o[ni] = __builtin_amdgcn_mfma_f32_16x16x32_bf16(pa[kh], bv, o[ni], 0, 0, 0);
      }
    }
  }
  // ---- epilogue: normalize; all-masked rows -> uniform over ALL S keys
#pragma unroll
  for (int r = 0; r < 4; ++r) {
    float inv = 1.0f / lrun[r];
    bool allm = (mrun[r] <= -1.0e8f);
    int row_g = qrow0 + r;
#pragma unroll
    for (int ni = 0; ni < 4; ++ni) {
      float val;
      if (allm)
        val = vsum[(b * 16 + hh) * 64 + ni * 16 + l15] * (1.0f / 2048.0f);
      else
        val = o[ni][r] * inv;
      ctx[(size_t)(b * S + row_g) * D + hh * 64 + ni * 16 + l15] = f2bf(val);
    }
  }
}

// ============================================================================
extern "C" void kernel_launch(void* const* d_in, const int* in_sizes, int n_in,
                              void* d_out, int out_size, void* d_ws,
                              size_t ws_size, hipStream_t stream) {
  (void)in_sizes; (void)n_in; (void)out_size; (void)ws_size;
  const float* x   = (const float*)d_in[0];
  const int*   am  = (const int*)d_in[1];
  const float* Wq  = (const float*)d_in[2];
  const float* bq  = (const float*)d_in[3];
  const float* Wk  = (const float*)d_in[4];
  const float* bk  = (const float*)d_in[5];
  const float* Wv  = (const float*)d_in[6];
  const float* bv  = (const float*)d_in[7];
  const float* Wo  = (const float*)d_in[8];
  const float* bo  = (const float*)d_in[9];
  const float* W1  = (const float*)d_in[10];
  const float* b1  = (const float*)d_in[11];
  const float* W2  = (const float*)d_in[12];
  const float* b2  = (const float*)d_in[13];
  const float* g1  = (const float*)d_in[14];
  const float* be1 = (const float*)d_in[15];
  const float* g2  = (const float*)d_in[16];
  const float* be2 = (const float*)d_in[17];
  float* out = (float*)d_out;

  unsigned char* w8 = (unsigned char*)d_ws;
  const size_t MB = 1024ull * 1024;
  unsigned short* WqT = (unsigned short*)(w8 + 0 * MB);
  unsigned short* WkT = (unsigned short*)(w8 + 2 * MB);
  unsigned short* WvT = (unsigned short*)(w8 + 4 * MB);
  unsigned short* WoT = (unsigned short*)(w8 + 6 * MB);
  unsigned short* W1T = (unsigned short*)(w8 + 8 * MB);
  unsigned short* W2T = (unsigned short*)(w8 + 16 * MB);
  unsigned short* h   = (unsigned short*)(w8 + 24 * MB);  // -> ctx
  unsigned short* q   = (unsigned short*)(w8 + 40 * MB);  // -> h2
  unsigned short* kb  = (unsigned short*)(w8 + 56 * MB);  // -> fc (32MB)
  unsigned short* v   = (unsigned short*)(w8 + 88 * MB);
  unsigned short* vT  = (unsigned short*)(w8 + 104 * MB);
  float*          vsm = (float*)(w8 + 120 * MB);
  unsigned short* ctx = h;
  unsigned short* h2  = q;
  unsigned short* fc  = kb;
  float*          x1  = out;

  transpose_cast<<<dim3(32, 32), 256, 0, stream>>>(Wq, WqT, 1024, 1024);
  transpose_cast<<<dim3(32, 32), 256, 0, stream>>>(Wk, WkT, 1024, 1024);
  transpose_cast<<<dim3(32, 32), 256, 0, stream>>>(Wv, WvT, 1024, 1024);
  transpose_cast<<<dim3(32, 32), 256, 0, stream>>>(Wo, WoT, 1024, 1024);
  transpose_cast<<<dim3(128, 32), 256, 0, stream>>>(W1, W1T, 1024, 4096);
  transpose_cast<<<dim3(32, 128), 256, 0, stream>>>(W2, W2T, 4096, 1024);

  ln_bf16<<<8192, 256, 0, stream>>>(x, g1, be1, h);
  gemm_bf16<1, 0, 0, 1><<<dim3(8, 64), 256, 0, stream>>>(
      h, WqT, bq, nullptr, q, 8192, 1024, 1024, 1024, 1024, 1024);
  gemm_bf16<1, 0, 0, 1><<<dim3(8, 64), 256, 0, stream>>>(
      h, WkT, bk, nullptr, kb, 8192, 1024, 1024, 1024, 1024, 1024);
  gemm_bf16<1, 0, 0, 1><<<dim3(8, 64), 256, 0, stream>>>(
      h, WvT, bv, nullptr, v, 8192, 1024, 1024, 1024, 1024, 1024);
  vtrans<<<dim3(32, 64), 256, 0, stream>>>(v, vT);
  vsum_k<<<64, 256, 0, stream>>>(vT, vsm);
  attn_mfma<<<dim3(32, 16, 4), 256, 0, stream>>>(q, kb, vT, am, vsm, ctx);
  gemm_bf16<1, 1, 0, 0><<<dim3(8, 64), 256, 0, stream>>>(
      ctx, WoT, bo, x, x1, 8192, 1024, 1024, 1024, 1024, 1024);
  ln_bf16<<<8192, 256, 0, stream>>>(x1, g2, be2, h2);
  for (int p = 0; p < 2; ++p) {
    gemm_bf16<1, 0, 1, 1><<<dim3(16, 64), 256, 0, stream>>>(
        h2, W1T + (size_t)p * 2048 * 1024, b1 + p * 2048, nullptr, fc,
        8192, 2048, 1024, 1024, 1024, 2048);
    if (p == 0) {
      gemm_bf16<1, 1, 0, 0><<<dim3(8, 64), 256, 0, stream>>>(
          fc, W2T + p * 2048, b2, x1, out, 8192, 1024, 2048, 2048, 4096, 1024);
    } else {
      gemm_bf16<0, 1, 0, 0><<<dim3(8, 64), 256, 0, stream>>>(
          fc, W2T + p * 2048, nullptr, out, out, 8192, 1024, 2048, 2048, 4096, 1024);
    }
  }
}

// Round 10
// 731.661 us; speedup vs baseline: 5.3190x; 1.0873x over previous
//
#include <hip/hip_runtime.h>
#include <math.h>

// ============================================================================
// Transformer block, round 10: verbatim resubmission of round-9 source (GPU
// acquisition timeout; kernel never executed). Fused-QKV GEMM + prefetch/
// double-buffered MFMA flash attention (__expf, Q-hoist, diag-only causal).
// B=4, S=2048, D=1024, H=16, dk=64, F=4096.
//
// Workspace (byte offsets, peak ~104 MB):
//   0  WqkvT bf16 [3072][1024] (6 MB)
//   6  WoT (2)   8 W1T (8)   16 W2T (8)
//   24 h bf16 (16)       -> ctx bf16
//   40 qkv bf16 [8192][3072] (48)  -> h2 (16 @40), fc (32 @56) after attn
//   88 vT bf16 (16) [bh][d][s]
//   104 vsum f32 (16 KB), then bqkv f32[3072] (12 KB)
//   d_out: x1 (attn residual f32), then final out (in-place res add, safe).
// ============================================================================

#define NEGV (-1.0e9f)

typedef short bfrag __attribute__((ext_vector_type(8)));   // 8 bf16 (4 VGPR)
typedef float ffrag __attribute__((ext_vector_type(4)));   // mfma f32x4 acc
typedef unsigned short usvec8 __attribute__((ext_vector_type(8)));

__device__ __forceinline__ unsigned short f2bf(float f) {  // RNE f32->bf16
  unsigned u = __float_as_uint(f);
  u += 0x7fffu + ((u >> 16) & 1u);
  return (unsigned short)(u >> 16);
}
__device__ __forceinline__ float bf2f(unsigned short h) {
  return __uint_as_float(((unsigned)h) << 16);
}
__device__ __forceinline__ float gelu_f(float v) {
  return 0.5f * v * (1.0f + erff(v * 0.7071067811865475f));
}
__device__ __forceinline__ void gload16(const void* g, void* l) {
  __builtin_amdgcn_global_load_lds(
      (const __attribute__((address_space(1))) void*)g,
      (__attribute__((address_space(3))) void*)l, 16, 0, 0);
}

// ------------------------------------------- weight transpose+cast fp32->bf16
__global__ __launch_bounds__(256) void transpose_cast(
    const float* __restrict__ src, unsigned short* __restrict__ dst,
    int R, int C) {
  __shared__ float tile[32][33];
  int bx = blockIdx.x, by = blockIdx.y;
  int tx = threadIdx.x & 31, ty = threadIdx.x >> 5;
#pragma unroll
  for (int i = 0; i < 4; ++i)
    tile[ty + i * 8][tx] =
        src[(size_t)(by * 32 + ty + i * 8) * C + bx * 32 + tx];
  __syncthreads();
#pragma unroll
  for (int i = 0; i < 4; ++i)
    dst[(size_t)(bx * 32 + ty + i * 8) * R + by * 32 + tx] =
        f2bf(tile[tx][ty + i * 8]);
}

// --------------------------------------------------- concat bq|bk|bv (f32)
__global__ __launch_bounds__(256) void bias_concat(
    const float* __restrict__ bq, const float* __restrict__ bk,
    const float* __restrict__ bv, float* __restrict__ dst) {
  int i = blockIdx.x * 256 + threadIdx.x;  // 12 blocks x 256 = 3072
  const float* src = (i < 1024) ? bq : (i < 2048 ? bk : bv);
  int off = (i < 1024) ? i : (i < 2048 ? i - 1024 : i - 2048);
  dst[i] = src[off];
}

// ---------------------------------------------------------------- LayerNorm
__global__ __launch_bounds__(256) void ln_bf16(
    const float* __restrict__ X, const float* __restrict__ G,
    const float* __restrict__ Bt, unsigned short* __restrict__ O) {
  int row = blockIdx.x, t = threadIdx.x;
  const float* xr = X + (size_t)row * 1024;
  float4 x4 = *(const float4*)(xr + t * 4);
  float s = x4.x + x4.y + x4.z + x4.w;
#pragma unroll
  for (int off = 1; off < 64; off <<= 1) s += __shfl_xor(s, off);
  __shared__ float p1[4], p2[4];
  int wv = t >> 6, ln = t & 63;
  if (ln == 0) p1[wv] = s;
  __syncthreads();
  float mu = (p1[0] + p1[1] + p1[2] + p1[3]) * (1.0f / 1024.0f);
  float d0 = x4.x - mu, d1 = x4.y - mu, d2 = x4.z - mu, d3 = x4.w - mu;
  float q = d0 * d0 + d1 * d1 + d2 * d2 + d3 * d3;
#pragma unroll
  for (int off = 1; off < 64; off <<= 1) q += __shfl_xor(q, off);
  if (ln == 0) p2[wv] = q;
  __syncthreads();
  float var = (p2[0] + p2[1] + p2[2] + p2[3]) * (1.0f / 1024.0f);
  float rstd = rsqrtf(var + 1e-5f);
  float4 g4 = *(const float4*)(G + t * 4);
  float4 b4 = *(const float4*)(Bt + t * 4);
  ushort4 o4;
  o4.x = f2bf(d0 * rstd * g4.x + b4.x);
  o4.y = f2bf(d1 * rstd * g4.y + b4.y);
  o4.z = f2bf(d2 * rstd * g4.z + b4.z);
  o4.w = f2bf(d3 * rstd * g4.w + b4.w);
  *(ushort4*)(O + (size_t)row * 1024 + t * 4) = o4;
}

// ---------------------------------------------------------------- MFMA GEMM
// (HW-verified r4/r8) C = A(bf16) @ BT^T (+bias)(+gelu)(+res).
template <int DO_BIAS, int DO_RES, int DO_GELU, int OUT_BF16>
__global__ __launch_bounds__(256) void gemm_bf16(
    const unsigned short* __restrict__ A, const unsigned short* __restrict__ BT,
    const float* __restrict__ bias, const float* __restrict__ res,
    void* __restrict__ Cv, int M, int N, int K, int lda, int ldbt, int ldc) {
  __shared__ short Asm[128 * 64];
  __shared__ short Bsm[128 * 64];
  const int t = threadIdx.x;
  const int wv = t >> 6, lane = t & 63;
  const int wm = wv >> 1, wn = wv & 1;
  const int bn0 = blockIdx.x * 128, bm0 = blockIdx.y * 128;
  const int srow = t >> 3, sunit = t & 7;
  ffrag acc[4][4];
#pragma unroll
  for (int i = 0; i < 4; ++i)
#pragma unroll
    for (int j = 0; j < 4; ++j) acc[i][j] = {0.f, 0.f, 0.f, 0.f};

  for (int kk = 0; kk < K; kk += 64) {
#pragma unroll
    for (int i = 0; i < 4; ++i) {
      int row = i * 32 + srow;
      int su = sunit ^ (row & 7);
      gload16(A + (size_t)(bm0 + row) * lda + kk + su * 8,
              Asm + i * 2048 + wv * 512);
    }
#pragma unroll
    for (int i = 0; i < 4; ++i) {
      int row = i * 32 + srow;
      int su = sunit ^ (row & 7);
      gload16(BT + (size_t)(bn0 + row) * ldbt + kk + su * 8,
              Bsm + i * 2048 + wv * 512);
    }
    asm volatile("s_waitcnt vmcnt(0)" ::: "memory");
    __syncthreads();
#pragma unroll
    for (int kh = 0; kh < 2; ++kh) {
      bfrag af[4], bf[4];
#pragma unroll
      for (int mi = 0; mi < 4; ++mi) {
        int row = wm * 64 + mi * 16 + (lane & 15);
        int u = (kh * 4 + (lane >> 4)) ^ (row & 7);
        af[mi] = *(const bfrag*)&Asm[row * 64 + u * 8];
      }
#pragma unroll
      for (int ni = 0; ni < 4; ++ni) {
        int row = wn * 64 + ni * 16 + (lane & 15);
        int u = (kh * 4 + (lane >> 4)) ^ (row & 7);
        bf[ni] = *(const bfrag*)&Bsm[row * 64 + u * 8];
      }
#pragma unroll
      for (int mi = 0; mi < 4; ++mi)
#pragma unroll
        for (int ni = 0; ni < 4; ++ni)
          acc[mi][ni] = __builtin_amdgcn_mfma_f32_16x16x32_bf16(
              af[mi], bf[ni], acc[mi][ni], 0, 0, 0);
    }
    __syncthreads();
  }
  const int crow0 = bm0 + wm * 64 + (lane >> 4) * 4;
  const int ccol0 = bn0 + wn * 64 + (lane & 15);
#pragma unroll
  for (int ni = 0; ni < 4; ++ni) {
    int col = ccol0 + ni * 16;
    float bi = DO_BIAS ? bias[col] : 0.0f;
#pragma unroll
    for (int mi = 0; mi < 4; ++mi) {
#pragma unroll
      for (int r = 0; r < 4; ++r) {
        int row = crow0 + mi * 16 + r;
        float v = acc[mi][ni][r] + bi;
        if (DO_GELU) v = gelu_f(v);
        if (DO_RES) v += res[(size_t)row * ldc + col];
        if (OUT_BF16)
          ((unsigned short*)Cv)[(size_t)row * ldc + col] = f2bf(v);
        else
          ((float*)Cv)[(size_t)row * ldc + col] = v;
      }
    }
  }
}

// ----------------------------------- V [token][ld] slice -> vT[bh][d][s]
__global__ __launch_bounds__(256) void vtrans(
    const unsigned short* __restrict__ V, unsigned short* __restrict__ VT,
    int ld) {
  __shared__ unsigned short tile[64 * 65];  // [d][s], odd stride
  int st = blockIdx.x, bh = blockIdx.y;
  int b = bh >> 4, hh = bh & 15;
  int t = threadIdx.x;
  int s0 = st * 64;
  int sr = t >> 3, u = t & 7;
#pragma unroll
  for (int p = 0; p < 2; ++p) {
    int s = p * 32 + sr;
    usvec8 vv = *(const usvec8*)(V + (size_t)(b * 2048 + s0 + s) * ld +
                                 hh * 64 + u * 8);
#pragma unroll
    for (int j = 0; j < 8; ++j) tile[(u * 8 + j) * 65 + s] = vv[j];
  }
  __syncthreads();
  int dr = t >> 2, c = t & 3;
#pragma unroll
  for (int p = 0; p < 2; ++p) {
    int su = p * 4 + c;
    usvec8 ov;
#pragma unroll
    for (int j = 0; j < 8; ++j) ov[j] = tile[dr * 65 + su * 8 + j];
    *(usvec8*)(VT + (size_t)bh * 64 * 2048 + (size_t)dr * 2048 + s0 + su * 8) =
        ov;
  }
}

// ------------------------------------------------- V column-sum from vT
__global__ __launch_bounds__(256) void vsum_k(
    const unsigned short* __restrict__ VT, float* __restrict__ vsum) {
  int bh = blockIdx.x;
  int t = threadIdx.x;
  int d = t >> 2, c = t & 3;
  const unsigned short* row = VT + (size_t)bh * 131072 + (size_t)d * 2048;
  float acc = 0.0f;
#pragma unroll 4
  for (int i = 0; i < 64; ++i) {
    usvec8 vv = *(const usvec8*)(row + c * 8 + i * 32);
#pragma unroll
    for (int j = 0; j < 8; ++j) acc += bf2f(vv[j]);
  }
  acc += __shfl_xor(acc, 1);
  acc += __shfl_xor(acc, 2);
  if (c == 0) vsum[bh * 64 + d] = acc;
}

// --------------------------------------------------- MFMA flash attention
// grid (S/64, H, B), 4 waves. Fragment conventions byte-identical to r8
// (HW-verified). vs r8: K/V double-buffered with next-tile prefetch (one
// vmcnt+barrier per tile), Q-frag hoisted, __expf, causal mask only on the
// diagonal tile. q/k read from fused qkv buffer at stride 3072.
__global__ __launch_bounds__(256) void attn_mfma(
    const unsigned short* __restrict__ QKV, const unsigned short* __restrict__ VT,
    const int* __restrict__ amask, const float* __restrict__ vsum,
    unsigned short* __restrict__ ctx) {
  const int S = 2048, LD = 3072, D = 1024;
  int qt = blockIdx.x, hh = blockIdx.y, b = blockIdx.z;
  int t = threadIdx.x;
  int wv = t >> 6, lane = t & 63;
  int l15 = lane & 15, l4 = lane >> 4;
  __shared__ short Qs[64 * 64];
  __shared__ short Ks[2][64 * 64];
  __shared__ short Vs[2][64 * 64];   // vT tiles: [d][kpos]
  __shared__ short Ps[4][16 * 64];
  const int srow = t >> 3, sunit = t & 7;

  const unsigned short* qb = QKV + (size_t)(b * S + qt * 64) * LD + hh * 64;
  const unsigned short* kbase = QKV + (size_t)b * S * LD + 1024 + hh * 64;
  const unsigned short* vtb = VT + (size_t)(b * 16 + hh) * 64 * 2048;

  // stage Q once + K/V tile 0 into buffer 0
#pragma unroll
  for (int i = 0; i < 2; ++i) {
    int row = i * 32 + srow;
    int su = sunit ^ (row & 7);
    gload16(qb + (size_t)row * LD + su * 8, Qs + i * 2048 + wv * 512);
    gload16(kbase + (size_t)row * LD + su * 8, &Ks[0][i * 2048 + wv * 512]);
    gload16(vtb + (size_t)row * 2048 + su * 8, &Vs[0][i * 2048 + wv * 512]);
  }
  asm volatile("s_waitcnt vmcnt(0)" ::: "memory");
  __syncthreads();

  // Q-hoist: A-fragment invariant across kt
  bfrag aq[2];
#pragma unroll
  for (int kh = 0; kh < 2; ++kh) {
    int row = wv * 16 + l15;
    int u = (kh * 4 + l4) ^ (row & 7);
    aq[kh] = *(const bfrag*)&Qs[row * 64 + u * 8];
  }

  ffrag o[4];
#pragma unroll
  for (int ni = 0; ni < 4; ++ni) o[ni] = {0.f, 0.f, 0.f, 0.f};
  float mrun[4] = {-INFINITY, -INFINITY, -INFINITY, -INFINITY};
  float lrun[4] = {0.f, 0.f, 0.f, 0.f};
  const int qrow0 = qt * 64 + wv * 16 + l4 * 4;
  int cur = 0;

  for (int kt = 0; kt <= qt; ++kt) {
    if (kt) {  // drain prefetched loads for buf[cur]; fence prev readers
      asm volatile("s_waitcnt vmcnt(0)" ::: "memory");
      __syncthreads();
    }
    if (kt < qt) {  // prefetch next tile into the other buffer
#pragma unroll
      for (int i = 0; i < 2; ++i) {
        int row = i * 32 + srow;
        int su = sunit ^ (row & 7);
        gload16(kbase + (size_t)((kt + 1) * 64 + row) * LD + su * 8,
                &Ks[cur ^ 1][i * 2048 + wv * 512]);
        gload16(vtb + (size_t)row * 2048 + (kt + 1) * 64 + su * 8,
                &Vs[cur ^ 1][i * 2048 + wv * 512]);
      }
    }
    const short* ksb = Ks[cur];
    const short* vsb = Vs[cur];

    // ---- QK^T: S[16q][64kpos] per wave
    float sv[4][4];  // [ni kpos-chunk][reg row]
#pragma unroll
    for (int ni = 0; ni < 4; ++ni) {
      ffrag sf = {0.f, 0.f, 0.f, 0.f};
#pragma unroll
      for (int kh = 0; kh < 2; ++kh) {
        int row = ni * 16 + l15;
        int u = (kh * 4 + l4) ^ (row & 7);
        bfrag bk = *(const bfrag*)&ksb[row * 64 + u * 8];
        sf = __builtin_amdgcn_mfma_f32_16x16x32_bf16(aq[kh], bk, sf, 0, 0, 0);
      }
#pragma unroll
      for (int r = 0; r < 4; ++r) sv[ni][r] = sf[r] * 0.125f;
    }
    // ---- masks: causal only on the diagonal tile; padding always
    if (kt == qt) {
#pragma unroll
      for (int ni = 0; ni < 4; ++ni) {
        int kpos = kt * 64 + ni * 16 + l15;
        int mk = amask[b * S + kpos];
#pragma unroll
        for (int r = 0; r < 4; ++r)
          if (mk == 0 || kpos > qrow0 + r) sv[ni][r] = NEGV;
      }
    } else {
#pragma unroll
      for (int ni = 0; ni < 4; ++ni) {
        int kpos = kt * 64 + ni * 16 + l15;
        int mk = amask[b * S + kpos];
        if (mk == 0) {
#pragma unroll
          for (int r = 0; r < 4; ++r) sv[ni][r] = NEGV;
        }
      }
    }
    // ---- online softmax (16-lane row groups), fast exp
    float alpha[4];
#pragma unroll
    for (int r = 0; r < 4; ++r) {
      float mt = fmaxf(fmaxf(sv[0][r], sv[1][r]), fmaxf(sv[2][r], sv[3][r]));
#pragma unroll
      for (int off = 1; off < 16; off <<= 1) mt = fmaxf(mt, __shfl_xor(mt, off));
      float mn = fmaxf(mrun[r], mt);
      alpha[r] = __expf(mrun[r] - mn);
      float rs = 0.0f;
#pragma unroll
      for (int ni = 0; ni < 4; ++ni) {
        float pv = __expf(sv[ni][r] - mn);
        sv[ni][r] = pv;
        rs += pv;
      }
#pragma unroll
      for (int off = 1; off < 16; off <<= 1) rs += __shfl_xor(rs, off);
      lrun[r] = lrun[r] * alpha[r] + rs;
      mrun[r] = mn;
    }
    // ---- P -> LDS bf16 (per-wave, swizzled)
#pragma unroll
    for (int ni = 0; ni < 4; ++ni) {
      int cu = ni * 2 + (l15 >> 3);
#pragma unroll
      for (int r = 0; r < 4; ++r) {
        int row = l4 * 4 + r;
        int su = cu ^ (row & 7);
        Ps[wv][row * 64 + su * 8 + (l15 & 7)] = f2bf(sv[ni][r]);
      }
    }
    // ---- PV: O[16q][64d] += P[16q][64kpos] * vT[d][kpos]^T
#pragma unroll
    for (int ni = 0; ni < 4; ++ni)
#pragma unroll
      for (int r = 0; r < 4; ++r) o[ni][r] *= alpha[r];
    bfrag pa[2];
#pragma unroll
    for (int kh = 0; kh < 2; ++kh) {
      int row = l15;
      int u = (kh * 4 + l4) ^ (row & 7);
      pa[kh] = *(const bfrag*)&Ps[wv][row * 64 + u * 8];
    }
#pragma unroll
    for (int ni = 0; ni < 4; ++ni) {
#pragma unroll
      for (int kh = 0; kh < 2; ++kh) {
        int drow = ni * 16 + l15;
        int u = (kh * 4 + l4) ^ (drow & 7);
        bfrag bv = *(const bfrag*)&vsb[drow * 64 + u * 8];
        o[ni] = __builtin_amdgcn_mfma_f32_16x16x32_bf16(pa[kh], bv, o[ni], 0, 0, 0);
      }
    }
    cur ^= 1;
  }
  // ---- epilogue: normalize; all-masked rows -> uniform over ALL S keys
#pragma unroll
  for (int r = 0; r < 4; ++r) {
    float inv = 1.0f / lrun[r];
    bool allm = (mrun[r] <= -1.0e8f);
    int row_g = qrow0 + r;
#pragma unroll
    for (int ni = 0; ni < 4; ++ni) {
      float val;
      if (allm)
        val = vsum[(b * 16 + hh) * 64 + ni * 16 + l15] * (1.0f / 2048.0f);
      else
        val = o[ni][r] * inv;
      ctx[(size_t)(b * S + row_g) * D + hh * 64 + ni * 16 + l15] = f2bf(val);
    }
  }
}

// ============================================================================
extern "C" void kernel_launch(void* const* d_in, const int* in_sizes, int n_in,
                              void* d_out, int out_size, void* d_ws,
                              size_t ws_size, hipStream_t stream) {
  (void)in_sizes; (void)n_in; (void)out_size; (void)ws_size;
  const float* x   = (const float*)d_in[0];
  const int*   am  = (const int*)d_in[1];
  const float* Wq  = (const float*)d_in[2];
  const float* bq  = (const float*)d_in[3];
  const float* Wk  = (const float*)d_in[4];
  const float* bk  = (const float*)d_in[5];
  const float* Wv  = (const float*)d_in[6];
  const float* bv  = (const float*)d_in[7];
  const float* Wo  = (const float*)d_in[8];
  const float* bo  = (const float*)d_in[9];
  const float* W1  = (const float*)d_in[10];
  const float* b1  = (const float*)d_in[11];
  const float* W2  = (const float*)d_in[12];
  const float* b2  = (const float*)d_in[13];
  const float* g1  = (const float*)d_in[14];
  const float* be1 = (const float*)d_in[15];
  const float* g2  = (const float*)d_in[16];
  const float* be2 = (const float*)d_in[17];
  float* out = (float*)d_out;

  unsigned char* w8 = (unsigned char*)d_ws;
  const size_t MB = 1024ull * 1024;
  unsigned short* WqkvT = (unsigned short*)(w8 + 0 * MB);   // [3072][1024]
  unsigned short* WoT   = (unsigned short*)(w8 + 6 * MB);
  unsigned short* W1T   = (unsigned short*)(w8 + 8 * MB);
  unsigned short* W2T   = (unsigned short*)(w8 + 16 * MB);
  unsigned short* h     = (unsigned short*)(w8 + 24 * MB);  // -> ctx
  unsigned short* qkv   = (unsigned short*)(w8 + 40 * MB);  // [8192][3072]
  unsigned short* vT    = (unsigned short*)(w8 + 88 * MB);
  float*          vsm   = (float*)(w8 + 104 * MB);
  float*          bqkv  = (float*)(w8 + 104 * MB + 16 * 1024);
  unsigned short* ctx = h;
  unsigned short* h2  = qkv;                                // reuse after attn
  unsigned short* fc  = (unsigned short*)(w8 + 56 * MB);    // reuse after attn
  float*          x1  = out;

  bias_concat<<<12, 256, 0, stream>>>(bq, bk, bv, bqkv);
  transpose_cast<<<dim3(32, 32), 256, 0, stream>>>(Wq, WqkvT, 1024, 1024);
  transpose_cast<<<dim3(32, 32), 256, 0, stream>>>(Wk, WqkvT + 1024 * 1024, 1024, 1024);
  transpose_cast<<<dim3(32, 32), 256, 0, stream>>>(Wv, WqkvT + 2048 * 1024, 1024, 1024);
  transpose_cast<<<dim3(32, 32), 256, 0, stream>>>(Wo, WoT, 1024, 1024);
  transpose_cast<<<dim3(128, 32), 256, 0, stream>>>(W1, W1T, 1024, 4096);
  transpose_cast<<<dim3(32, 128), 256, 0, stream>>>(W2, W2T, 4096, 1024);

  ln_bf16<<<8192, 256, 0, stream>>>(x, g1, be1, h);
  // fused QKV: [8192][3072]
  gemm_bf16<1, 0, 0, 1><<<dim3(24, 64), 256, 0, stream>>>(
      h, WqkvT, bqkv, nullptr, qkv, 8192, 3072, 1024, 1024, 1024, 3072);
  vtrans<<<dim3(32, 64), 256, 0, stream>>>(qkv + 2048, vT, 3072);
  vsum_k<<<64, 256, 0, stream>>>(vT, vsm);
  attn_mfma<<<dim3(32, 16, 4), 256, 0, stream>>>(qkv, vT, am, vsm, ctx);
  gemm_bf16<1, 1, 0, 0><<<dim3(8, 64), 256, 0, stream>>>(
      ctx, WoT, bo, x, x1, 8192, 1024, 1024, 1024, 1024, 1024);
  ln_bf16<<<8192, 256, 0, stream>>>(x1, g2, be2, h2);
  for (int p = 0; p < 2; ++p) {
    gemm_bf16<1, 0, 1, 1><<<dim3(16, 64), 256, 0, stream>>>(
        h2, W1T + (size_t)p * 2048 * 1024, b1 + p * 2048, nullptr, fc,
        8192, 2048, 1024, 1024, 1024, 2048);
    if (p == 0) {
      gemm_bf16<1, 1, 0, 0><<<dim3(8, 64), 256, 0, stream>>>(
          fc, W2T + p * 2048, b2, x1, out, 8192, 1024, 2048, 2048, 4096, 1024);
    } else {
      gemm_bf16<0, 1, 0, 0><<<dim3(8, 64), 256, 0, stream>>>(
          fc, W2T + p * 2048, nullptr, out, out, 8192, 1024, 2048, 2048, 4096, 1024);
    }
  }
}